// Round 10
// baseline (46.367 us; speedup 1.0000x reference)
//
#include <hip/hip_runtime.h>
#include <math.h>

#define B_ 16
#define T_ 24
#define N_ 300
#define E_ 9600
#define H_ 3
#define F_ 8
#define HF_ 24
#define GRUH_ 16
#define OUTB_ 7200   // NUM_AIRPORTS * HORIZON
#define CPB_ 2       // chunks (blocks) per graph
#define NPC_ 150     // nodes per chunk

// ====== K1: histogram + scan, 1 block x 1024, unrolled loads for MLP ================
__global__ __launch_bounds__(1024) void hist_kernel(
    const int* __restrict__ dst, int* __restrict__ rp, int* __restrict__ off_g)
{
    __shared__ int cnt[N_];
    const int tid = threadIdx.x;
    for (int i = tid; i < N_; i += 1024) cnt[i] = 0;
    __syncthreads();
    // 9600 = 9*1024 + 384: fixed 9 iters (unrolled, loads prefetched) + tail
    int v[9];
    #pragma unroll
    for (int k = 0; k < 9; ++k) v[k] = dst[tid + k * 1024];
    const int vt = (tid < E_ - 9 * 1024) ? dst[tid + 9 * 1024] : -1;
    #pragma unroll
    for (int k = 0; k < 9; ++k) atomicAdd(&cnt[v[k]], 1);
    if (vt >= 0) atomicAdd(&cnt[vt], 1);
    __syncthreads();
    if (tid < 64) {                       // wave 0 scans 300 counts in 5 chunks
        int base = 0;
        for (int c = 0; c < 5; ++c) {
            int i = c * 64 + tid;
            int orig = (i < N_) ? cnt[i] : 0;
            int s = orig;
            #pragma unroll
            for (int o = 1; o < 64; o <<= 1) {
                int u = __shfl_up(s, o, 64);
                if (tid >= o) s += u;
            }
            if (i < N_) { int ex = base + s - orig; rp[i] = ex; off_g[i] = ex; }
            base += __shfl(s, 63, 64);
        }
        if (tid == 0) rp[N_] = base;
    }
}

// ====== K2: scatter, one edge per thread, distributed over 38 blocks ================
__global__ __launch_bounds__(256) void scatter_kernel(
    const int* __restrict__ src, const int* __restrict__ dst,
    int* __restrict__ off_g, unsigned* __restrict__ pk)
{
    const int i = blockIdx.x * 256 + threadIdx.x;
    if (i < E_) {
        const int d = dst[i];
        const int pos = atomicAdd(&off_g[d], 1);
        pk[pos] = (unsigned)i | ((unsigned)src[i] << 17);
    }
}

// ====== K3: EdgeGAT partial sums; 2 blocks/graph, heads fused, XCD swizzle ==========
__global__ __launch_bounds__(320) void gat_kernel(
    const float* __restrict__ x, const float* __restrict__ ew,
    const float* __restrict__ Wn, const float* __restrict__ We,
    const float* __restrict__ al, const float* __restrict__ ar,
    const float* __restrict__ ae,
    const int* __restrict__ rp_g, const unsigned* __restrict__ pk_g,
    float* __restrict__ Spart)
{
    __shared__ float xs[N_];
    __shared__ int rp_l[N_ + 1];
    __shared__ float cf[9];
    __shared__ float Sred[5][3];

    // XCD swizzle: launch L -> (g,c) with L%8 == g%8 so both chunks share an XCD L2.
    const int L = blockIdx.x;
    const int m = L >> 3;
    const int c = m & 1;
    const int g = (L & 7) + 8 * (m >> 1);
    const int tid = threadIdx.x;
    const long base_e = (long)g * E_;
    const int  base_n = g * N_;

    for (int i = tid; i < N_; i += 320) xs[i] = x[base_n + i];
    for (int i = tid; i <= N_; i += 320) rp_l[i] = rp_g[i];
    if (tid < H_) {
        int h = tid;
        float cl = 0.f, cr = 0.f, ce = 0.f;
        #pragma unroll
        for (int f = 0; f < F_; ++f) {
            float wn = Wn[h * F_ + f];
            cl += wn * al[h * F_ + f];
            cr += wn * ar[h * F_ + f];
            ce += We[h * F_ + f] * ae[h * F_ + f];
        }
        cf[h] = cl; cf[3 + h] = cr; cf[6 + h] = ce;
    }
    __syncthreads();

    float n0 = 0.f, d0 = 0.f, n1 = 0.f, d1 = 0.f, n2 = 0.f, d2 = 0.f;
    if (tid < 2 * NPC_) {
        const int n = c * NPC_ + (tid >> 1);
        const int half = tid & 1;
        const float xd = xs[n];
        const float c0l = cf[0], c1l = cf[1], c2l = cf[2];
        const float c0r = cf[3], c1r = cf[4], c2r = cf[5];
        const float c0e = cf[6], c1e = cf[7], c2e = cf[8];
        const int p1 = rp_l[n + 1];
        for (int p = rp_l[n] + half; p < p1; p += 2) {
            unsigned pkv = pk_g[p];
            float w = ew[base_e + (pkv & 0x1FFFFu)];
            float xsv = xs[pkv >> 17];
            float e0 = fmaf(xsv, c0l, fmaf(xd, c0r, w * c0e)); e0 = e0 > 0.f ? e0 : 0.2f * e0;
            float e1 = fmaf(xsv, c1l, fmaf(xd, c1r, w * c1e)); e1 = e1 > 0.f ? e1 : 0.2f * e1;
            float e2 = fmaf(xsv, c2l, fmaf(xd, c2r, w * c2e)); e2 = e2 > 0.f ? e2 : 0.2f * e2;
            float p0 = __expf(e0), pe1 = __expf(e1), pe2 = __expf(e2);
            d0 += p0;  n0 += p0 * xsv;
            d1 += pe1; n1 += pe1 * xsv;
            d2 += pe2; n2 += pe2 * xsv;
        }
    }
    // combine the node's two half-threads
    n0 += __shfl_xor(n0, 1); d0 += __shfl_xor(d0, 1);
    n1 += __shfl_xor(n1, 1); d1 += __shfl_xor(d1, 1);
    n2 += __shfl_xor(n2, 1); d2 += __shfl_xor(d2, 1);
    float a0 = 0.f, a1 = 0.f, a2 = 0.f;
    if (tid < 2 * NPC_ && (tid & 1) == 0) {
        a0 = d0 > 0.f ? n0 / d0 : 0.f;
        a1 = d1 > 0.f ? n1 / d1 : 0.f;
        a2 = d2 > 0.f ? n2 / d2 : 0.f;
    }
    for (int o = 32; o; o >>= 1) {
        a0 += __shfl_down(a0, o);
        a1 += __shfl_down(a1, o);
        a2 += __shfl_down(a2, o);
    }
    const int wave = tid >> 6, lane = tid & 63;
    if (lane == 0) { Sred[wave][0] = a0; Sred[wave][1] = a1; Sred[wave][2] = a2; }
    __syncthreads();
    if (tid < 3)
        Spart[g * (CPB_ * 3) + c * 3 + tid] =
            Sred[0][tid] + Sred[1][tid] + Sred[2][tid] + Sred[3][tid] + Sred[4][tid];
}

// ====== K4: FC with replicated-GRU prologue ==========================================
// Each block spans at most 2 batch values (b0, b0+1). Wave 0 computes their final
// hidden states via the 16-lane shuffle recurrence (lanes 0-15 -> b0, 16-31 -> b0+1),
// broadcasts through LDS, then all threads do the FC slice.
__global__ __launch_bounds__(256) void fc_kernel(
    const float* __restrict__ Spart, const float* __restrict__ Wn,
    const float* __restrict__ gb, const float* __restrict__ Wih,
    const float* __restrict__ bih, const float* __restrict__ Whh,
    const float* __restrict__ bhh, const float* __restrict__ Wfc,
    const float* __restrict__ bfc, float* __restrict__ out)
{
    __shared__ float hS[2][GRUH_];
    const int tid = threadIdx.x;
    const int idx0 = blockIdx.x * 256;
    const int b0 = idx0 / OUTB_;

    if (tid < 64) {
        const int grp = tid >> 4;            // 0..3 (only 0,1 used)
        const int u = tid & 15;
        const int gbase = tid & ~15;         // shuffle-group base lane
        const bool active = (grp < 2) && (b0 + grp < B_);
        const int bb = active ? (b0 + grp) : b0;

        float whr[GRUH_], whz[GRUH_], whn[GRUH_];
        #pragma unroll
        for (int k = 0; k < GRUH_; ++k) {
            whr[k] = Whh[u * GRUH_ + k];
            whz[k] = Whh[(16 + u) * GRUH_ + k];
            whn[k] = Whh[(32 + u) * GRUH_ + k];
        }
        const float bhr = bhh[u], bhz = bhh[16 + u], bhn = bhh[32 + u];

        float A[3][3], C[3];
        #pragma unroll
        for (int r = 0; r < 3; ++r) {
            const int j = r * 16 + u;
            float cc = bih[j];
            A[r][0] = A[r][1] = A[r][2] = 0.f;
            #pragma unroll
            for (int k = 0; k < HF_; ++k) {
                float wk = Wih[j * HF_ + k];
                cc += wk * gb[k];
                A[r][k >> 3] += wk * Wn[k];
            }
            C[r] = cc;
        }

        float h = 0.f;
        for (int t = 0; t < T_; ++t) {
            const float* sp = Spart + (bb * T_ + t) * (CPB_ * 3);
            float S0 = (sp[0] + sp[3]) * (1.0f / N_);
            float S1 = (sp[1] + sp[4]) * (1.0f / N_);
            float S2 = (sp[2] + sp[5]) * (1.0f / N_);
            float gr = C[0] + A[0][0] * S0 + A[0][1] * S1 + A[0][2] * S2;
            float gz = C[1] + A[1][0] * S0 + A[1][1] * S1 + A[1][2] * S2;
            float gn = C[2] + A[2][0] * S0 + A[2][1] * S1 + A[2][2] * S2;
            float hr = bhr, hz = bhz, hn = bhn;
            #pragma unroll
            for (int k = 0; k < GRUH_; ++k) {
                float hk = __shfl(h, gbase + k, 64);
                hr += whr[k] * hk;
                hz += whz[k] * hk;
                hn += whn[k] * hk;
            }
            float r = 1.f / (1.f + __expf(-(gr + hr)));
            float z = 1.f / (1.f + __expf(-(gz + hz)));
            float n = tanhf(gn + r * hn);
            h = (1.f - z) * n + z * h;
        }
        if (active) hS[grp][u] = h;
    }
    __syncthreads();

    const int idx = idx0 + tid;
    if (idx < B_ * OUTB_) {
        const int b = idx / OUTB_, o = idx - b * OUTB_;
        const float4* wr = (const float4*)(Wfc + (long)o * GRUH_);
        const float* hr = hS[b - b0];
        float4 w0 = wr[0], w1 = wr[1], w2 = wr[2], w3 = wr[3];
        float acc = bfc[o];
        acc += hr[0]  * w0.x + hr[1]  * w0.y + hr[2]  * w0.z + hr[3]  * w0.w;
        acc += hr[4]  * w1.x + hr[5]  * w1.y + hr[6]  * w1.z + hr[7]  * w1.w;
        acc += hr[8]  * w2.x + hr[9]  * w2.y + hr[10] * w2.z + hr[11] * w2.w;
        acc += hr[12] * w3.x + hr[13] * w3.y + hr[14] * w3.z + hr[15] * w3.w;
        out[idx] = acc;
    }
}

extern "C" void kernel_launch(void* const* d_in, const int* in_sizes, int n_in,
                              void* d_out, int out_size, void* d_ws, size_t ws_size,
                              hipStream_t stream) {
    const float* x    = (const float*)d_in[0];
    const float* ew   = (const float*)d_in[1];
    const float* Wn   = (const float*)d_in[2];
    const float* We   = (const float*)d_in[3];
    const float* al   = (const float*)d_in[4];
    const float* ar   = (const float*)d_in[5];
    const float* ae   = (const float*)d_in[6];
    const float* gb   = (const float*)d_in[7];
    const float* Wih  = (const float*)d_in[8];
    const float* Whh  = (const float*)d_in[9];
    const float* bih  = (const float*)d_in[10];
    const float* bhh  = (const float*)d_in[11];
    const float* Wfc  = (const float*)d_in[12];
    const float* bfc  = (const float*)d_in[13];
    const int*   src  = (const int*)d_in[14];
    const int*   dst  = (const int*)d_in[15];
    float* out = (float*)d_out;

    // ws layout
    int* rp    = (int*)d_ws;                            // [301] (pad to 320)
    int* off_g = rp + 320;                              // [300] (pad to 320)
    unsigned* pk = (unsigned*)(off_g + 320);            // [9600]
    float* Spart = (float*)(pk + E_);                   // [384*2*3]

    hist_kernel<<<1, 1024, 0, stream>>>(dst, rp, off_g);
    scatter_kernel<<<(E_ + 255) / 256, 256, 0, stream>>>(src, dst, off_g, pk);
    gat_kernel<<<B_ * T_ * CPB_, 320, 0, stream>>>(x, ew, Wn, We, al, ar, ae,
                                                   rp, pk, Spart);
    fc_kernel<<<(B_ * OUTB_ + 255) / 256, 256, 0, stream>>>(Spart, Wn, gb, Wih, bih,
                                                            Whh, bhh, Wfc, bfc, out);
}

// Round 11
// 45.925 us; speedup vs baseline: 1.0096x; 1.0096x over previous
//
#include <hip/hip_runtime.h>
#include <math.h>

#define B_ 16
#define T_ 24
#define N_ 300
#define E_ 9600
#define H_ 3
#define F_ 8
#define HF_ 24
#define GRUH_ 16
#define OUTB_ 7200   // NUM_AIRPORTS * HORIZON
#define CPB_ 4       // chunks (blocks) per graph
#define NPC_ 75      // nodes per chunk
#define QPN_ 4       // threads per node

// ====== K1: CSR build, one block x 1024 threads (validated R8/R9 version) ===========
__global__ __launch_bounds__(1024) void csr_kernel(
    const int* __restrict__ src, const int* __restrict__ dst,
    int* __restrict__ rp, unsigned* __restrict__ pk)
{
    __shared__ int cnt[N_], off[N_];
    const int tid = threadIdx.x;
    for (int i = tid; i < N_; i += 1024) cnt[i] = 0;
    __syncthreads();
    for (int i = tid; i < E_; i += 1024) atomicAdd(&cnt[dst[i]], 1);
    __syncthreads();
    if (tid < 64) {                       // wave 0 scans 300 counts in 5 chunks
        int base = 0;
        for (int c = 0; c < 5; ++c) {
            int i = c * 64 + tid;
            int orig = (i < N_) ? cnt[i] : 0;
            int v = orig;
            #pragma unroll
            for (int o = 1; o < 64; o <<= 1) {
                int u = __shfl_up(v, o, 64);
                if (tid >= o) v += u;
            }
            if (i < N_) { int ex = base + v - orig; off[i] = ex; rp[i] = ex; }
            base += __shfl(v, 63, 64);
        }
        if (tid == 0) rp[N_] = base;
    }
    __syncthreads();
    for (int i = tid; i < E_; i += 1024) {
        int d = dst[i];
        int pos = atomicAdd(&off[d], 1);
        pk[pos] = (unsigned)i | ((unsigned)src[i] << 17);
    }
}

// ====== K2: EdgeGAT partial sums; 4 blocks/graph, 4 threads/node, XCD swizzle =======
__global__ __launch_bounds__(320) void gat_kernel(
    const float* __restrict__ x, const float* __restrict__ ew,
    const float* __restrict__ Wn, const float* __restrict__ We,
    const float* __restrict__ al, const float* __restrict__ ar,
    const float* __restrict__ ae,
    const int* __restrict__ rp_g, const unsigned* __restrict__ pk_g,
    float* __restrict__ Spart)
{
    __shared__ float xs[N_];
    __shared__ int rp_l[N_ + 1];
    __shared__ float cf[9];
    __shared__ float Sred[5][3];

    // XCD swizzle: all 4 chunks of graph g land on XCD g%8. Bijective for grid 1536.
    const int L = blockIdx.x;
    const int g = (L & 7) + 8 * (L >> 5);
    const int c = (L >> 3) & 3;
    const int tid = threadIdx.x;
    const long base_e = (long)g * E_;
    const int  base_n = g * N_;

    for (int i = tid; i < N_; i += 320) xs[i] = x[base_n + i];
    for (int i = tid; i <= N_; i += 320) rp_l[i] = rp_g[i];
    if (tid < H_) {
        int h = tid;
        float cl = 0.f, cr = 0.f, ce = 0.f;
        #pragma unroll
        for (int f = 0; f < F_; ++f) {
            float wn = Wn[h * F_ + f];
            cl += wn * al[h * F_ + f];
            cr += wn * ar[h * F_ + f];
            ce += We[h * F_ + f] * ae[h * F_ + f];
        }
        cf[h] = cl; cf[3 + h] = cr; cf[6 + h] = ce;
    }
    __syncthreads();

    float n0 = 0.f, d0 = 0.f, n1 = 0.f, d1 = 0.f, n2 = 0.f, d2 = 0.f;
    if (tid < QPN_ * NPC_) {
        const int n = c * NPC_ + (tid >> 2);
        const int q = tid & 3;
        const float xd = xs[n];
        const float c0l = cf[0], c1l = cf[1], c2l = cf[2];
        const float c0r = cf[3], c1r = cf[4], c2r = cf[5];
        const float c0e = cf[6], c1e = cf[7], c2e = cf[8];
        const int p1 = rp_l[n + 1];
        for (int p = rp_l[n] + q; p < p1; p += QPN_) {
            unsigned pkv = pk_g[p];
            float w = ew[base_e + (pkv & 0x1FFFFu)];
            float xsv = xs[pkv >> 17];
            float e0 = fmaf(xsv, c0l, fmaf(xd, c0r, w * c0e)); e0 = e0 > 0.f ? e0 : 0.2f * e0;
            float e1 = fmaf(xsv, c1l, fmaf(xd, c1r, w * c1e)); e1 = e1 > 0.f ? e1 : 0.2f * e1;
            float e2 = fmaf(xsv, c2l, fmaf(xd, c2r, w * c2e)); e2 = e2 > 0.f ? e2 : 0.2f * e2;
            float p0 = __expf(e0), pe1 = __expf(e1), pe2 = __expf(e2);
            d0 += p0;  n0 += p0 * xsv;
            d1 += pe1; n1 += pe1 * xsv;
            d2 += pe2; n2 += pe2 * xsv;
        }
    }
    // combine the node's four quarter-threads (two butterfly levels)
    n0 += __shfl_xor(n0, 1); d0 += __shfl_xor(d0, 1);
    n1 += __shfl_xor(n1, 1); d1 += __shfl_xor(d1, 1);
    n2 += __shfl_xor(n2, 1); d2 += __shfl_xor(d2, 1);
    n0 += __shfl_xor(n0, 2); d0 += __shfl_xor(d0, 2);
    n1 += __shfl_xor(n1, 2); d1 += __shfl_xor(d1, 2);
    n2 += __shfl_xor(n2, 2); d2 += __shfl_xor(d2, 2);
    float a0 = 0.f, a1 = 0.f, a2 = 0.f;
    if (tid < QPN_ * NPC_ && (tid & 3) == 0) {
        a0 = d0 > 0.f ? n0 / d0 : 0.f;
        a1 = d1 > 0.f ? n1 / d1 : 0.f;
        a2 = d2 > 0.f ? n2 / d2 : 0.f;
    }
    for (int o = 32; o; o >>= 1) {
        a0 += __shfl_down(a0, o);
        a1 += __shfl_down(a1, o);
        a2 += __shfl_down(a2, o);
    }
    const int wave = tid >> 6, lane = tid & 63;
    if (lane == 0) { Sred[wave][0] = a0; Sred[wave][1] = a1; Sred[wave][2] = a2; }
    __syncthreads();
    if (tid < 3)
        Spart[g * (CPB_ * 3) + c * 3 + tid] =
            Sred[0][tid] + Sred[1][tid] + Sred[2][tid] + Sred[3][tid] + Sred[4][tid];
}

// ====== K3: FC with replicated-GRU prologue ==========================================
__global__ __launch_bounds__(256) void fc_kernel(
    const float* __restrict__ Spart, const float* __restrict__ Wn,
    const float* __restrict__ gb, const float* __restrict__ Wih,
    const float* __restrict__ bih, const float* __restrict__ Whh,
    const float* __restrict__ bhh, const float* __restrict__ Wfc,
    const float* __restrict__ bfc, float* __restrict__ out)
{
    __shared__ float hS[2][GRUH_];
    const int tid = threadIdx.x;
    const int idx0 = blockIdx.x * 256;
    const int b0 = idx0 / OUTB_;

    if (tid < 64) {
        const int grp = tid >> 4;            // 0..3 (only 0,1 used)
        const int u = tid & 15;
        const int gbase = tid & ~15;         // shuffle-group base lane
        const bool active = (grp < 2) && (b0 + grp < B_);
        const int bb = active ? (b0 + grp) : b0;

        float whr[GRUH_], whz[GRUH_], whn[GRUH_];
        #pragma unroll
        for (int k = 0; k < GRUH_; ++k) {
            whr[k] = Whh[u * GRUH_ + k];
            whz[k] = Whh[(16 + u) * GRUH_ + k];
            whn[k] = Whh[(32 + u) * GRUH_ + k];
        }
        const float bhr = bhh[u], bhz = bhh[16 + u], bhn = bhh[32 + u];

        float A[3][3], C[3];
        #pragma unroll
        for (int r = 0; r < 3; ++r) {
            const int j = r * 16 + u;
            float cc = bih[j];
            A[r][0] = A[r][1] = A[r][2] = 0.f;
            #pragma unroll
            for (int k = 0; k < HF_; ++k) {
                float wk = Wih[j * HF_ + k];
                cc += wk * gb[k];
                A[r][k >> 3] += wk * Wn[k];
            }
            C[r] = cc;
        }

        float h = 0.f;
        for (int t = 0; t < T_; ++t) {
            const float* sp = Spart + (bb * T_ + t) * (CPB_ * 3);
            float S0 = (sp[0] + sp[3] + sp[6] + sp[9])  * (1.0f / N_);
            float S1 = (sp[1] + sp[4] + sp[7] + sp[10]) * (1.0f / N_);
            float S2 = (sp[2] + sp[5] + sp[8] + sp[11]) * (1.0f / N_);
            float gr = C[0] + A[0][0] * S0 + A[0][1] * S1 + A[0][2] * S2;
            float gz = C[1] + A[1][0] * S0 + A[1][1] * S1 + A[1][2] * S2;
            float gn = C[2] + A[2][0] * S0 + A[2][1] * S1 + A[2][2] * S2;
            float hr = bhr, hz = bhz, hn = bhn;
            #pragma unroll
            for (int k = 0; k < GRUH_; ++k) {
                float hk = __shfl(h, gbase + k, 64);
                hr += whr[k] * hk;
                hz += whz[k] * hk;
                hn += whn[k] * hk;
            }
            float r = 1.f / (1.f + __expf(-(gr + hr)));
            float z = 1.f / (1.f + __expf(-(gz + hz)));
            float n = tanhf(gn + r * hn);
            h = (1.f - z) * n + z * h;
        }
        if (active) hS[grp][u] = h;
    }
    __syncthreads();

    const int idx = idx0 + tid;
    if (idx < B_ * OUTB_) {
        const int b = idx / OUTB_, o = idx - b * OUTB_;
        const float4* wr = (const float4*)(Wfc + (long)o * GRUH_);
        const float* hr = hS[b - b0];
        float4 w0 = wr[0], w1 = wr[1], w2 = wr[2], w3 = wr[3];
        float acc = bfc[o];
        acc += hr[0]  * w0.x + hr[1]  * w0.y + hr[2]  * w0.z + hr[3]  * w0.w;
        acc += hr[4]  * w1.x + hr[5]  * w1.y + hr[6]  * w1.z + hr[7]  * w1.w;
        acc += hr[8]  * w2.x + hr[9]  * w2.y + hr[10] * w2.z + hr[11] * w2.w;
        acc += hr[12] * w3.x + hr[13] * w3.y + hr[14] * w3.z + hr[15] * w3.w;
        out[idx] = acc;
    }
}

extern "C" void kernel_launch(void* const* d_in, const int* in_sizes, int n_in,
                              void* d_out, int out_size, void* d_ws, size_t ws_size,
                              hipStream_t stream) {
    const float* x    = (const float*)d_in[0];
    const float* ew   = (const float*)d_in[1];
    const float* Wn   = (const float*)d_in[2];
    const float* We   = (const float*)d_in[3];
    const float* al   = (const float*)d_in[4];
    const float* ar   = (const float*)d_in[5];
    const float* ae   = (const float*)d_in[6];
    const float* gb   = (const float*)d_in[7];
    const float* Wih  = (const float*)d_in[8];
    const float* Whh  = (const float*)d_in[9];
    const float* bih  = (const float*)d_in[10];
    const float* bhh  = (const float*)d_in[11];
    const float* Wfc  = (const float*)d_in[12];
    const float* bfc  = (const float*)d_in[13];
    const int*   src  = (const int*)d_in[14];
    const int*   dst  = (const int*)d_in[15];
    float* out = (float*)d_out;

    // ws layout
    int* rp = (int*)d_ws;                               // [301] (pad to 320)
    unsigned* pk = (unsigned*)(rp + 320);               // [9600]
    float* Spart = (float*)(pk + E_);                   // [384*4*3]

    csr_kernel<<<1, 1024, 0, stream>>>(src, dst, rp, pk);
    gat_kernel<<<B_ * T_ * CPB_, 320, 0, stream>>>(x, ew, Wn, We, al, ar, ae,
                                                   rp, pk, Spart);
    fc_kernel<<<(B_ * OUTB_ + 255) / 256, 256, 0, stream>>>(Spart, Wn, gb, Wih, bih,
                                                            Whh, bhh, Wfc, bfc, out);
}

// Round 12
// 45.912 us; speedup vs baseline: 1.0099x; 1.0003x over previous
//
#include <hip/hip_runtime.h>
#include <math.h>

#define B_ 16
#define T_ 24
#define N_ 300
#define E_ 9600
#define H_ 3
#define F_ 8
#define HF_ 24
#define GRUH_ 16
#define OUTB_ 7200   // NUM_AIRPORTS * HORIZON
#define CPB_ 2       // chunks (blocks) per graph
#define NPC_ 150     // nodes per chunk
#define NW_ 16       // waves in csr block

// ====== K1: CSR build with per-wave sub-histograms (16x less atomic serialization) ==
__global__ __launch_bounds__(1024) void csr_kernel(
    const int* __restrict__ src, const int* __restrict__ dst,
    int* __restrict__ rp, unsigned* __restrict__ pk)
{
    __shared__ int cnt[NW_ * N_];   // per-wave histograms -> per-wave exclusive prefixes
    __shared__ int tot[N_];
    __shared__ int rps[N_ + 1];
    const int tid = threadIdx.x;
    const int w = tid >> 6;

    for (int i = tid; i < NW_ * N_; i += 1024) cnt[i] = 0;
    __syncthreads();
    // histogram: each wave into its own copy (within-wave contention only)
    for (int i = tid; i < E_; i += 1024) atomicAdd(&cnt[w * N_ + dst[i]], 1);
    __syncthreads();
    // column-wise exclusive prefix over waves; tot[n] = total count
    if (tid < N_) {
        int run = 0;
        #pragma unroll
        for (int k = 0; k < NW_; ++k) {
            int t = cnt[k * N_ + tid];
            cnt[k * N_ + tid] = run;
            run += t;
        }
        tot[tid] = run;
    }
    __syncthreads();
    // wave 0: exclusive scan of tot -> rps
    if (tid < 64) {
        int base = 0;
        for (int c = 0; c < 5; ++c) {
            int i = c * 64 + tid;
            int orig = (i < N_) ? tot[i] : 0;
            int v = orig;
            #pragma unroll
            for (int o = 1; o < 64; o <<= 1) {
                int u = __shfl_up(v, o, 64);
                if (tid >= o) v += u;
            }
            if (i < N_) rps[i] = base + v - orig;
            base += __shfl(v, 63, 64);
        }
        if (tid == 0) rps[N_] = base;
    }
    __syncthreads();
    for (int i = tid; i <= N_; i += 1024) rp[i] = rps[i];
    // scatter: same tid->wave mapping as histogram, so per-wave ranges line up
    for (int i = tid; i < E_; i += 1024) {
        int d = dst[i];
        int pos = rps[d] + atomicAdd(&cnt[w * N_ + d], 1);
        pk[pos] = (unsigned)i | ((unsigned)src[i] << 17);
    }
}

// ====== K2: EdgeGAT partial sums; 2 blocks/graph, heads fused, XCD swizzle ==========
__global__ __launch_bounds__(320) void gat_kernel(
    const float* __restrict__ x, const float* __restrict__ ew,
    const float* __restrict__ Wn, const float* __restrict__ We,
    const float* __restrict__ al, const float* __restrict__ ar,
    const float* __restrict__ ae,
    const int* __restrict__ rp_g, const unsigned* __restrict__ pk_g,
    float* __restrict__ Spart)
{
    __shared__ float xs[N_];
    __shared__ int rp_l[N_ + 1];
    __shared__ float cf[9];
    __shared__ float Sred[5][3];

    // XCD swizzle: launch L -> (g,c) with L%8 == g%8 so both chunks share an XCD L2.
    const int L = blockIdx.x;
    const int m = L >> 3;
    const int c = m & 1;
    const int g = (L & 7) + 8 * (m >> 1);
    const int tid = threadIdx.x;
    const long base_e = (long)g * E_;
    const int  base_n = g * N_;

    for (int i = tid; i < N_; i += 320) xs[i] = x[base_n + i];
    for (int i = tid; i <= N_; i += 320) rp_l[i] = rp_g[i];
    if (tid < H_) {
        int h = tid;
        float cl = 0.f, cr = 0.f, ce = 0.f;
        #pragma unroll
        for (int f = 0; f < F_; ++f) {
            float wn = Wn[h * F_ + f];
            cl += wn * al[h * F_ + f];
            cr += wn * ar[h * F_ + f];
            ce += We[h * F_ + f] * ae[h * F_ + f];
        }
        cf[h] = cl; cf[3 + h] = cr; cf[6 + h] = ce;
    }
    __syncthreads();

    float n0 = 0.f, d0 = 0.f, n1 = 0.f, d1 = 0.f, n2 = 0.f, d2 = 0.f;
    if (tid < 2 * NPC_) {
        const int n = c * NPC_ + (tid >> 1);
        const int half = tid & 1;
        const float xd = xs[n];
        const float c0l = cf[0], c1l = cf[1], c2l = cf[2];
        const float c0r = cf[3], c1r = cf[4], c2r = cf[5];
        const float c0e = cf[6], c1e = cf[7], c2e = cf[8];
        const int p1 = rp_l[n + 1];
        for (int p = rp_l[n] + half; p < p1; p += 2) {
            unsigned pkv = pk_g[p];
            float w = ew[base_e + (pkv & 0x1FFFFu)];
            float xsv = xs[pkv >> 17];
            float e0 = fmaf(xsv, c0l, fmaf(xd, c0r, w * c0e)); e0 = e0 > 0.f ? e0 : 0.2f * e0;
            float e1 = fmaf(xsv, c1l, fmaf(xd, c1r, w * c1e)); e1 = e1 > 0.f ? e1 : 0.2f * e1;
            float e2 = fmaf(xsv, c2l, fmaf(xd, c2r, w * c2e)); e2 = e2 > 0.f ? e2 : 0.2f * e2;
            float p0 = __expf(e0), pe1 = __expf(e1), pe2 = __expf(e2);
            d0 += p0;  n0 += p0 * xsv;
            d1 += pe1; n1 += pe1 * xsv;
            d2 += pe2; n2 += pe2 * xsv;
        }
    }
    // combine the node's two half-threads
    n0 += __shfl_xor(n0, 1); d0 += __shfl_xor(d0, 1);
    n1 += __shfl_xor(n1, 1); d1 += __shfl_xor(d1, 1);
    n2 += __shfl_xor(n2, 1); d2 += __shfl_xor(d2, 1);
    float a0 = 0.f, a1 = 0.f, a2 = 0.f;
    if (tid < 2 * NPC_ && (tid & 1) == 0) {
        a0 = d0 > 0.f ? n0 / d0 : 0.f;
        a1 = d1 > 0.f ? n1 / d1 : 0.f;
        a2 = d2 > 0.f ? n2 / d2 : 0.f;
    }
    for (int o = 32; o; o >>= 1) {
        a0 += __shfl_down(a0, o);
        a1 += __shfl_down(a1, o);
        a2 += __shfl_down(a2, o);
    }
    const int wave = tid >> 6, lane = tid & 63;
    if (lane == 0) { Sred[wave][0] = a0; Sred[wave][1] = a1; Sred[wave][2] = a2; }
    __syncthreads();
    if (tid < 3)
        Spart[g * (CPB_ * 3) + c * 3 + tid] =
            Sred[0][tid] + Sred[1][tid] + Sred[2][tid] + Sred[3][tid] + Sred[4][tid];
}

// ====== K3: FC with replicated-GRU prologue ==========================================
__global__ __launch_bounds__(256) void fc_kernel(
    const float* __restrict__ Spart, const float* __restrict__ Wn,
    const float* __restrict__ gb, const float* __restrict__ Wih,
    const float* __restrict__ bih, const float* __restrict__ Whh,
    const float* __restrict__ bhh, const float* __restrict__ Wfc,
    const float* __restrict__ bfc, float* __restrict__ out)
{
    __shared__ float hS[2][GRUH_];
    const int tid = threadIdx.x;
    const int idx0 = blockIdx.x * 256;
    const int b0 = idx0 / OUTB_;

    if (tid < 64) {
        const int grp = tid >> 4;            // 0..3 (only 0,1 used)
        const int u = tid & 15;
        const int gbase = tid & ~15;         // shuffle-group base lane
        const bool active = (grp < 2) && (b0 + grp < B_);
        const int bb = active ? (b0 + grp) : b0;

        float whr[GRUH_], whz[GRUH_], whn[GRUH_];
        #pragma unroll
        for (int k = 0; k < GRUH_; ++k) {
            whr[k] = Whh[u * GRUH_ + k];
            whz[k] = Whh[(16 + u) * GRUH_ + k];
            whn[k] = Whh[(32 + u) * GRUH_ + k];
        }
        const float bhr = bhh[u], bhz = bhh[16 + u], bhn = bhh[32 + u];

        float A[3][3], C[3];
        #pragma unroll
        for (int r = 0; r < 3; ++r) {
            const int j = r * 16 + u;
            float cc = bih[j];
            A[r][0] = A[r][1] = A[r][2] = 0.f;
            #pragma unroll
            for (int k = 0; k < HF_; ++k) {
                float wk = Wih[j * HF_ + k];
                cc += wk * gb[k];
                A[r][k >> 3] += wk * Wn[k];
            }
            C[r] = cc;
        }

        float h = 0.f;
        for (int t = 0; t < T_; ++t) {
            const float* sp = Spart + (bb * T_ + t) * (CPB_ * 3);
            float S0 = (sp[0] + sp[3]) * (1.0f / N_);
            float S1 = (sp[1] + sp[4]) * (1.0f / N_);
            float S2 = (sp[2] + sp[5]) * (1.0f / N_);
            float gr = C[0] + A[0][0] * S0 + A[0][1] * S1 + A[0][2] * S2;
            float gz = C[1] + A[1][0] * S0 + A[1][1] * S1 + A[1][2] * S2;
            float gn = C[2] + A[2][0] * S0 + A[2][1] * S1 + A[2][2] * S2;
            float hr = bhr, hz = bhz, hn = bhn;
            #pragma unroll
            for (int k = 0; k < GRUH_; ++k) {
                float hk = __shfl(h, gbase + k, 64);
                hr += whr[k] * hk;
                hz += whz[k] * hk;
                hn += whn[k] * hk;
            }
            float r = 1.f / (1.f + __expf(-(gr + hr)));
            float z = 1.f / (1.f + __expf(-(gz + hz)));
            float n = tanhf(gn + r * hn);
            h = (1.f - z) * n + z * h;
        }
        if (active) hS[grp][u] = h;
    }
    __syncthreads();

    const int idx = idx0 + tid;
    if (idx < B_ * OUTB_) {
        const int b = idx / OUTB_, o = idx - b * OUTB_;
        const float4* wr = (const float4*)(Wfc + (long)o * GRUH_);
        const float* hr = hS[b - b0];
        float4 w0 = wr[0], w1 = wr[1], w2 = wr[2], w3 = wr[3];
        float acc = bfc[o];
        acc += hr[0]  * w0.x + hr[1]  * w0.y + hr[2]  * w0.z + hr[3]  * w0.w;
        acc += hr[4]  * w1.x + hr[5]  * w1.y + hr[6]  * w1.z + hr[7]  * w1.w;
        acc += hr[8]  * w2.x + hr[9]  * w2.y + hr[10] * w2.z + hr[11] * w2.w;
        acc += hr[12] * w3.x + hr[13] * w3.y + hr[14] * w3.z + hr[15] * w3.w;
        out[idx] = acc;
    }
}

extern "C" void kernel_launch(void* const* d_in, const int* in_sizes, int n_in,
                              void* d_out, int out_size, void* d_ws, size_t ws_size,
                              hipStream_t stream) {
    const float* x    = (const float*)d_in[0];
    const float* ew   = (const float*)d_in[1];
    const float* Wn   = (const float*)d_in[2];
    const float* We   = (const float*)d_in[3];
    const float* al   = (const float*)d_in[4];
    const float* ar   = (const float*)d_in[5];
    const float* ae   = (const float*)d_in[6];
    const float* gb   = (const float*)d_in[7];
    const float* Wih  = (const float*)d_in[8];
    const float* Whh  = (const float*)d_in[9];
    const float* bih  = (const float*)d_in[10];
    const float* bhh  = (const float*)d_in[11];
    const float* Wfc  = (const float*)d_in[12];
    const float* bfc  = (const float*)d_in[13];
    const int*   src  = (const int*)d_in[14];
    const int*   dst  = (const int*)d_in[15];
    float* out = (float*)d_out;

    // ws layout
    int* rp = (int*)d_ws;                               // [301] (pad to 320)
    unsigned* pk = (unsigned*)(rp + 320);               // [9600]
    float* Spart = (float*)(pk + E_);                   // [384*2*3]

    csr_kernel<<<1, 1024, 0, stream>>>(src, dst, rp, pk);
    gat_kernel<<<B_ * T_ * CPB_, 320, 0, stream>>>(x, ew, Wn, We, al, ar, ae,
                                                   rp, pk, Spart);
    fc_kernel<<<(B_ * OUTB_ + 255) / 256, 256, 0, stream>>>(Spart, Wn, gb, Wih, bih,
                                                            Whh, bhh, Wfc, bfc, out);
}